// Round 6
// baseline (9624.294 us; speedup 1.0000x reference)
//
#include <hip/hip_runtime.h>

#define NT 832
#define TSEQ 512

typedef float float2v __attribute__((ext_vector_type(2)));

__device__ __forceinline__ float sigmoid_(float x) { return 1.0f / (1.0f + __expf(-x)); }
__device__ __forceinline__ float tanh_(float x) { return 1.0f - 2.0f / (1.0f + __expf(2.0f * x)); }

template <int CTRL>
__device__ __forceinline__ float dppmv(float x) {
    return __int_as_float(__builtin_amdgcn_update_dpp(
        0, __float_as_int(x), CTRL, 0xF, 0xF, true));
}

// ---------------- prep kernel ----------------
// Task map (main): thread tid = p*16 + f; p = unit pair [0,50), f = k-chunk [0,16).
// Thread owns 8 gate-rows (units 2p,2p+1 x gates i,f,g,o) over k in [14f, 14f+14)
// of the padded K=224 image: l==0: [x(5); h(100); 0], l>=1: [x(100); h(100); 0].
// wflat[r*14+c], r in [0,8): r<4 -> unit 2p gate r; r>=4 -> unit 2p+1 gate r-4.
// Stored as 28 float4 per thread: wbuf[(l*28 + q)*832 + tid] = wflat[4q..4q+3].
extern "C" __global__ void prep_weights(const float* __restrict__ Wih0,
                                        const float* __restrict__ Whh0,
                                        const float* __restrict__ WihL,
                                        const float* __restrict__ WhhL,
                                        float4* __restrict__ wbuf) {
    int gid = blockIdx.x * 256 + threadIdx.x;  // 5*28*832 = 116480 total
    if (gid >= 116480) return;
    int tid = gid % 832;
    int ql = gid / 832;
    int q = ql % 28;
    int l = ql / 28;
    int p = tid / 16, f = tid % 16;
    float tmp[4] = {0.f, 0.f, 0.f, 0.f};
    if (tid < 800) {
        for (int j = 0; j < 4; ++j) {
            int e = 4 * q + j;            // 0..111
            int r = e / 14, cc = e % 14;
            int unit = 2 * p + (r >= 4 ? 1 : 0);
            int gate = r & 3;
            int row = gate * 100 + unit;
            int k = 14 * f + cc;          // 0..223
            float w = 0.f;
            if (l == 0) {
                if (k < 5) w = Wih0[row * 5 + k];
                else if (k < 105) w = Whh0[row * 100 + (k - 5)];
            } else {
                if (k < 100) w = WihL[(l - 1) * 40000 + row * 100 + k];
                else if (k < 200) w = WhhL[(l - 1) * 40000 + row * 100 + (k - 100)];
            }
            tmp[j] = w;
        }
    }
    wbuf[gid] = make_float4(tmp[0], tmp[1], tmp[2], tmp[3]);
}

// ---------------- main kernel ----------------
// One block per batch element; double-buffered xh (2x224 floats) -> 1 barrier/step.
// DPP butterfly reduces the 16 k-chunk partials within each 16-lane row (no LDS).
template <int IN, bool FIRST, bool STORE>
__device__ void run_layer(const float4* __restrict__ wl, const float* __restrict__ bL,
                          const float* __restrict__ xsrc, float* __restrict__ hdst,
                          int b, int tid, int f, int myu, bool real,
                          float* bufs) {
    float4 wq[28];
#pragma unroll
    for (int q = 0; q < 28; ++q) wq[q] = wl[q * 832 + tid];

    float bi = 0.f, bff = 0.f, bgg = 0.f, boo = 0.f;
    if (real) {
        bi = bL[myu]; bff = bL[100 + myu]; bgg = bL[200 + myu]; boo = bL[300 + myu];
    }

    for (int i = tid; i < 448; i += NT) bufs[i] = 0.f;
    __syncthreads();
    if (FIRST) {
        if (tid < 5) bufs[tid] = xsrc[b * TSEQ * 5 + tid];
    } else {
        if (tid < 25) ((float4*)bufs)[tid] = ((const float4*)xsrc)[b * TSEQ * 25 + tid];
    }
    __syncthreads();

    float c = 0.f, hprev = 0.f;
#pragma unroll 1
    for (int t = 0; t < TSEQ; ++t) {
        float* cur = bufs + (t & 1) * 224;
        float* nxt = bufs + ((t + 1) & 1) * 224;

        // delayed global h-store (in flight during FMA; drained by end barrier)
        if (STORE) {
            if (real && f < 2 && t > 0) hdst[(b * TSEQ + t - 1) * 100 + myu] = hprev;
        }
        // prefetch next-step input
        int tn = (t + 1 < TSEQ) ? t + 1 : TSEQ - 1;
        float pfs = 0.f;
        float4 pf4 = make_float4(0.f, 0.f, 0.f, 0.f);
        if (FIRST) {
            if (tid >= 128 && tid < 133) pfs = xsrc[(b * TSEQ + tn) * 5 + (tid - 128)];
        } else {
            if (tid >= 128 && tid < 153) pf4 = ((const float4*)xsrc)[(b * TSEQ + tn) * 25 + (tid - 128)];
        }

        // read my 14-float chunk (16 distinct banks across the row -> conflict-free)
        const float2v* xp = (const float2v*)(cur + 14 * f);
        float2v xr[7];
#pragma unroll
        for (int i = 0; i < 7; ++i) xr[i] = xp[i];

        // 112 MACs as 56 v_pk_fma_f32 (pairs never straddle a float4: r*14+2c is even)
        float2v acc[8];
#pragma unroll
        for (int r = 0; r < 8; ++r) acc[r] = (float2v){0.f, 0.f};
#pragma unroll
        for (int cc = 0; cc < 7; ++cc) {
#pragma unroll
            for (int r = 0; r < 8; ++r) {
                int e = r * 14 + 2 * cc;
                float2v wp = ((e & 2) == 0) ? (float2v){wq[e >> 2].x, wq[e >> 2].y}
                                            : (float2v){wq[e >> 2].z, wq[e >> 2].w};
                acc[r] = __builtin_elementwise_fma(wp, xr[cc], acc[r]);
            }
        }
        float a[8];
#pragma unroll
        for (int r = 0; r < 8; ++r) a[r] = acc[r].x + acc[r].y;

        // 4-step DPP butterfly over the 16-lane row: xor1, xor2, half_mirror, mirror
#pragma unroll
        for (int r = 0; r < 8; ++r) a[r] += dppmv<0xB1>(a[r]);   // quad_perm(1,0,3,2)
#pragma unroll
        for (int r = 0; r < 8; ++r) a[r] += dppmv<0x4E>(a[r]);   // quad_perm(2,3,0,1)
#pragma unroll
        for (int r = 0; r < 8; ++r) a[r] += dppmv<0x141>(a[r]);  // row_half_mirror
#pragma unroll
        for (int r = 0; r < 8; ++r) a[r] += dppmv<0x140>(a[r]);  // row_mirror

        // each lane handles ONE unit (parity of f): activations + state update
        bool odd = (f & 1) != 0;
        float si = (odd ? a[4] : a[0]) + bi;
        float sf = (odd ? a[5] : a[1]) + bff;
        float sg = (odd ? a[6] : a[2]) + bgg;
        float so = (odd ? a[7] : a[3]) + boo;
        float gi = sigmoid_(si);
        float gf = sigmoid_(sf);
        float gg = tanh_(sg);
        float go = sigmoid_(so);
        c = gf * c + gi * gg;
        float hv = go * tanh_(c);

        if (real && f < 2) nxt[IN + myu] = hv;   // lanes f=0,1 publish h for 2p,2p+1
        if (FIRST) {
            if (tid >= 128 && tid < 133) nxt[tid - 128] = pfs;
        } else {
            if (tid >= 128 && tid < 153) ((float4*)nxt)[tid - 128] = pf4;
        }
        hprev = hv;
        __syncthreads();
    }
    if (STORE) {
        if (real && f < 2) hdst[(b * TSEQ + TSEQ - 1) * 100 + myu] = hprev;
    }
}

extern "C" __global__ void __launch_bounds__(NT, 1)
gesture_lstm_kernel(const float* __restrict__ x,
                    const float4* __restrict__ wbuf,
                    const float* __restrict__ b0, const float* __restrict__ bLv,
                    const float* __restrict__ gamma, const float* __restrict__ beta,
                    const float* __restrict__ rmean, const float* __restrict__ rvar,
                    const float* __restrict__ W1, const float* __restrict__ b1,
                    const float* __restrict__ W2, const float* __restrict__ b2,
                    const float* __restrict__ W3, const float* __restrict__ b3,
                    float* __restrict__ out, float* __restrict__ hseq) {
    __shared__ __align__(16) float bufs[448];   // two 224-float xh buffers
    __shared__ __align__(16) float hw[10000];

    int tid = threadIdx.x;
    int b = blockIdx.x;
    int p = tid / 16;
    int f = tid % 16;
    int myu = 2 * p + (f & 1);
    bool real = tid < 800;

    run_layer<5,   true,  true >(wbuf + 0 * 23296, b0,         x,    hseq, b, tid, f, myu, real, bufs);
    run_layer<100, false, true >(wbuf + 1 * 23296, bLv + 0,    hseq, hseq, b, tid, f, myu, real, bufs);
    run_layer<100, false, true >(wbuf + 2 * 23296, bLv + 400,  hseq, hseq, b, tid, f, myu, real, bufs);
    run_layer<100, false, true >(wbuf + 3 * 23296, bLv + 800,  hseq, hseq, b, tid, f, myu, real, bufs);
    run_layer<100, false, false>(wbuf + 4 * 23296, bLv + 1200, hseq, hseq, b, tid, f, myu, real, bufs);

    // final h is in bufs[100..200) (t=511 wrote buffer 0, IN=100)
    // ---- head: BN (inference) -> FC1+ReLU -> FC2+ReLU -> FC3 ----
    if (tid < 100) {
        float hv = bufs[100 + tid];
        bufs[224 + tid] = (hv - rmean[tid]) * rsqrtf(rvar[tid] + 1e-5f) * gamma[tid] + beta[tid];
    }
    __syncthreads();

    for (int i = tid; i < 2500; i += NT) ((float4*)hw)[i] = ((const float4*)W1)[i];
    __syncthreads();
    if (tid < 100) {
        float acc = b1[tid];
#pragma unroll
        for (int k = 0; k < 100; ++k) acc = fmaf(hw[tid * 100 + k], bufs[224 + k], acc);
        bufs[tid] = fmaxf(acc, 0.0f);
    }
    __syncthreads();

    for (int i = tid; i < 2500; i += NT) ((float4*)hw)[i] = ((const float4*)W2)[i];
    __syncthreads();
    if (tid < 100) {
        float acc = b2[tid];
#pragma unroll
        for (int k = 0; k < 100; ++k) acc = fmaf(hw[tid * 100 + k], bufs[k], acc);
        bufs[224 + tid] = fmaxf(acc, 0.0f);
    }
    __syncthreads();

    if (tid < 3) {
        float acc = b3[tid];
#pragma unroll
        for (int k = 0; k < 100; ++k) acc = fmaf(W3[tid * 100 + k], bufs[224 + k], acc);
        out[b * 3 + tid] = acc;
    }
}

extern "C" void kernel_launch(void* const* d_in, const int* in_sizes, int n_in,
                              void* d_out, int out_size, void* d_ws, size_t ws_size,
                              hipStream_t stream) {
    const float* x     = (const float*)d_in[0];
    const float* Wih0  = (const float*)d_in[1];
    const float* Whh0  = (const float*)d_in[2];
    const float* b0    = (const float*)d_in[3];
    const float* WihL  = (const float*)d_in[4];
    const float* WhhL  = (const float*)d_in[5];
    const float* bLv   = (const float*)d_in[6];
    const float* gamma = (const float*)d_in[7];
    const float* beta  = (const float*)d_in[8];
    const float* rmean = (const float*)d_in[9];
    const float* rvar  = (const float*)d_in[10];
    const float* W1    = (const float*)d_in[11];
    const float* b1    = (const float*)d_in[12];
    const float* W2    = (const float*)d_in[13];
    const float* b2    = (const float*)d_in[14];
    const float* W3    = (const float*)d_in[15];
    const float* b3    = (const float*)d_in[16];

    float4* wbuf = (float4*)d_ws;                        // 116480 float4 = 1.864 MB
    float* hseq  = (float*)((char*)d_ws + 116480 * 16);  // 256*512*100 fp32 = 52.4 MB

    prep_weights<<<dim3(455), dim3(256), 0, stream>>>(Wih0, Whh0, WihL, WhhL, wbuf);
    gesture_lstm_kernel<<<dim3(256), dim3(NT), 0, stream>>>(
        x, wbuf, b0, bLv, gamma, beta, rmean, rvar, W1, b1, W2, b2, W3, b3,
        (float*)d_out, hseq);
}